// Round 9
// baseline (345.770 us; speedup 1.0000x reference)
//
#include <hip/hip_runtime.h>

#define UNITS 14336
#define IN_F 4096
#define PACKED 1024
#define CLIP_VAL 100.0f

typedef unsigned int uint32;

using bf16x8 = __attribute__((ext_vector_type(8))) short;   // 8 bf16 = 4 VGPRs
using f32x4  = __attribute__((ext_vector_type(4))) float;   // 4 fp32 acc

// fp32 -> bf16 round-to-nearest-even
__device__ inline unsigned short f2bf(float f) {
    uint32 u = __float_as_uint(f);
    u += 0x7FFFu + ((u >> 16) & 1u);
    return (unsigned short)(u >> 16);
}

__device__ inline uint32 pack2bf(float a, float b) {
    return (uint32)f2bf(a) | ((uint32)f2bf(b) << 16);
}

// SWAR unpack: one packed byte (int32 value 0..255, 4 crumbs little-endian)
// -> two uint32, each holding 2 bf16: r0 = {bf(c0), bf(c1)}, r1 = {bf(c2), bf(c3)}.
// crumb->bf16: 0->0x0000, 1->0x3F80 (+1), 2->0xBF80 (-1), 3->0x8000 (-0.0, harmless in MAC)
__device__ inline void unpack_byte(int v, uint32& r0, uint32& r1) {
    uint32 t0 = ((uint32)v & 3u) | (((uint32)v & 0xCu) << 14);         // c0 @ [1:0], c1 @ [17:16]
    uint32 t1 = (((uint32)v >> 4) & 3u) | (((uint32)v & 0xC0u) << 10); // c2, c3
    uint32 s0 = t0 >> 1;
    uint32 s1 = t1 >> 1;
    uint32 nz0 = (t0 ^ s0) & 0x00010001u;
    uint32 nz1 = (t1 ^ s1) & 0x00010001u;
    r0 = nz0 * 0x3F80u + ((s0 & 0x00010001u) << 15);
    r1 = nz1 * 0x3F80u + ((s1 & 0x00010001u) << 15);
}

__device__ inline float clipf(float y) {
    return fminf(fmaxf(y, -CLIP_VAL), CLIP_VAL);
}

// k-permuted fragment layout (unchanged):
// "group" g in [0,64) covers original k in [g*64, g*64+64).
// Within a group, lane quad q and k-step s in {0,1}:
//   MFMA k-slot q*8+j  <->  original k = g*64 + q*16 + s*8 + j
// pw side: lane(q,n) needs dwordx4 = int32 elements {P..P+3}, P = g*16 + q*4
//   (= 16-B granule #(g*4+q) of unit row n). Elements P,P+1 -> step s=0,
//   elements P+2,P+3 -> step s=1.
// x side: granule idx = g*256 + s*128 + h*64 + lane holds 8 bf16:
//   j -> x[h*16 + (lane&15)][g*64 + (lane>>4)*16 + s*8 + j]

// Kernel 1: convert x fp32 -> bf16 permuted fragments, replicated 8x
// (one copy per XCD-heuristic slot; MM block reads copy blockIdx&7).
__global__ __launch_bounds__(256) void convert_x_kernel(
    const float* __restrict__ x, uint4* __restrict__ ws) {
    int b = blockIdx.x;                          // 0..511
    int c = b & 7;                               // copy id
    int t = ((b >> 3) << 8) + threadIdx.x;       // granule 0..16383
    int lane = t & 63;
    int h = (t >> 6) & 1;
    int s = (t >> 7) & 1;
    int g = t >> 8;
    int n = lane & 15;
    int q = lane >> 4;
    int bi = h * 16 + n;
    int k0 = g * 64 + q * 16 + s * 8;
    const float4* src = (const float4*)(x + (size_t)bi * IN_F + k0);
    float4 lo = src[0];
    float4 hi = src[1];
    uint4 o;
    o.x = pack2bf(lo.x, lo.y);
    o.y = pack2bf(lo.z, lo.w);
    o.z = pack2bf(hi.x, hi.y);
    o.w = pack2bf(hi.z, hi.w);
    ws[c * 16384 + t] = o;
}

// Kernel 2: MFMA GEMM, v9 — DIAGNOSTIC A/B vs R7.
// R8's contiguous-LDS-DMA streaming structure, amplified with the exact same
// reps=8 instrument as R7 (acc carried across reps, epilogue folds 1/reps,
// identical work every call). R7 (scattered VGPR loads) measured 312 us,
// 2.7 TB/s, 650 MB FETCH. If contiguity fixed the streaming rate this
// dispatch lands ~100-130 us at 5-6.5 TB/s; if it repeats ~300 us the cap is
// not the global pattern.
// Grid: 896 blocks x 1024 threads (16 waves). Block tile: 16 units x 32
// batches, K-split 16. 64 KB LDS -> 2 blocks/CU, 32 waves/CU.
__global__ __launch_bounds__(1024, 8) void ternary_mm_kernel(
    const uint4* __restrict__ xw,     // 8 replicated copies of permuted x frags
    const int*   __restrict__ pw,     // [UNITS][PACKED] packed bytes as int32
    const float* __restrict__ scale,
    const float* __restrict__ bias,
    float*       __restrict__ out,
    int reps) {
    __shared__ int lds[16384];        // 64 KB: linear pw tile, later reduce buf

    const int tid  = threadIdx.x;
    const int wid  = tid >> 6;           // 0..15 = K-split index
    const int lane = tid & 63;
    const int q    = lane >> 4;          // quad 0..3
    const int n    = lane & 15;
    const int u0   = blockIdx.x << 4;    // 16 units per block
    const int g0   = wid << 2;           // first group (of 64 total)

    f32x4 acc0 = {0.f,0.f,0.f,0.f};      // batches h0 (0-15)
    f32x4 acc1 = {0.f,0.f,0.f,0.f};      // batches h1 (16-31)

    const char*  srcpw = (const char*)(pw + (size_t)u0 * PACKED);
    const uint4* xb = xw + ((blockIdx.x & 7) * 16384) + (g0 << 8) + lane;
    // fragment read: row n, granule g*4+q  ->  byte n*4096 + (g*4+q)*16
    const char*  lb = (const char*)lds + (n << 12) + (q << 4);

    for (int r = 0; r < reps; ++r) {
        // ---- stage 64 KB pw tile linearly: 4 rounds x 16 waves x 1 KB ----
        #pragma unroll
        for (int rr = 0; rr < 4; ++rr) {
            const int off = ((rr * 16 + wid) << 10) + (lane << 4);
            __builtin_amdgcn_global_load_lds(
                (const __attribute__((address_space(1))) uint32*)(srcpw + off),
                (__attribute__((address_space(3))) uint32*)((char*)lds + off),
                16, 0, 0);
        }
        __syncthreads();                 // DMA drained + cross-wave visibility

        #pragma unroll
        for (int i = 0; i < 4; ++i) {
            uint4 x00 = xb[(i << 8)];            // s=0, h=0
            uint4 x01 = xb[(i << 8) + 64];       // s=0, h=1
            uint4 x10 = xb[(i << 8) + 128];      // s=1, h=0
            uint4 x11 = xb[(i << 8) + 192];      // s=1, h=1
            int4 w4 = *(const int4*)(lb + ((g0 + i) << 6));    // ds_read_b128

            uint4 fA, fB;                        // step 0 / step 1 weight frags
            unpack_byte(w4.x, fA.x, fA.y);
            unpack_byte(w4.y, fA.z, fA.w);
            unpack_byte(w4.z, fB.x, fB.y);
            unpack_byte(w4.w, fB.z, fB.w);
            bf16x8 vA = __builtin_bit_cast(bf16x8, fA);
            bf16x8 vB = __builtin_bit_cast(bf16x8, fB);

            acc0 = __builtin_amdgcn_mfma_f32_16x16x32_bf16(
                __builtin_bit_cast(bf16x8, x00), vA, acc0, 0, 0, 0);
            acc1 = __builtin_amdgcn_mfma_f32_16x16x32_bf16(
                __builtin_bit_cast(bf16x8, x01), vA, acc1, 0, 0, 0);
            acc0 = __builtin_amdgcn_mfma_f32_16x16x32_bf16(
                __builtin_bit_cast(bf16x8, x10), vB, acc0, 0, 0, 0);
            acc1 = __builtin_amdgcn_mfma_f32_16x16x32_bf16(
                __builtin_bit_cast(bf16x8, x11), vB, acc1, 0, 0, 0);
        }
        __syncthreads();                 // protect LDS before next rep's stage
    }

    f32x4* red = (f32x4*)lds;            // [16 waves][2 h][64 lanes] = 32 KB
    red[(wid * 2 + 0) * 64 + lane] = acc0;
    red[(wid * 2 + 1) * 64 + lane] = acc1;
    __syncthreads();

    // Reduce 16 K-partials + epilogue. 128 active threads, one per (h, lane).
    if (tid < 128) {
        const float inv = 1.0f / (float)reps;    // exact for power-of-2 reps
        const int h = tid >> 6;
        const int l = tid & 63;
        f32x4 s = red[h * 64 + l];
        #pragma unroll
        for (int w = 1; w < 16; ++w) {
            f32x4 v = red[(w * 2 + h) * 64 + l];
            s[0] += v[0]; s[1] += v[1]; s[2] += v[2]; s[3] += v[3];
        }
        const int u  = u0 + (l & 15);
        const int b0 = h * 16 + ((l >> 4) << 2);   // row = (lane>>4)*4 + reg
        const float sc = scale[u] * inv;
        const float bi = bias[u];
        float* o = out + (size_t)b0 * UNITS + u;
        o[0 * UNITS] = clipf(s[0] * sc + bi);
        o[1 * UNITS] = clipf(s[1] * sc + bi);
        o[2 * UNITS] = clipf(s[2] * sc + bi);
        o[3 * UNITS] = clipf(s[3] * sc + bi);
    }
}

extern "C" void kernel_launch(void* const* d_in, const int* in_sizes, int n_in,
                              void* d_out, int out_size, void* d_ws, size_t ws_size,
                              hipStream_t stream) {
    const float* x     = (const float*)d_in[0];
    const int*   pw    = (const int*)d_in[1];
    const float* scale = (const float*)d_in[2];
    const float* bias  = (const float*)d_in[3];
    float* out = (float*)d_out;

    // ws usage: 8 copies x 256 KB permuted bf16 x fragments = 2 MB
    uint4* xw = (uint4*)d_ws;

    convert_x_kernel<<<512, 256, 0, stream>>>(x, xw);
    // reps=8: diagnostic amplification, A/B against R7's 312 us dispatch.
    ternary_mm_kernel<<<UNITS / 16, 1024, 0, stream>>>(xw, pw, scale, bias, out, 8);
}

// Round 11
// 103.049 us; speedup vs baseline: 3.3554x; 3.3554x over previous
//
#include <hip/hip_runtime.h>

#define UNITS 14336
#define IN_F 4096
#define PACKED 1024
#define CLIP_VAL 100.0f

typedef unsigned int uint32;

using bf16x8 = __attribute__((ext_vector_type(8))) short;   // 8 bf16 = 4 VGPRs
using f32x4  = __attribute__((ext_vector_type(4))) float;   // 4 fp32 acc

// fp32 -> bf16 round-to-nearest-even
__device__ inline unsigned short f2bf(float f) {
    uint32 u = __float_as_uint(f);
    u += 0x7FFFu + ((u >> 16) & 1u);
    return (unsigned short)(u >> 16);
}

__device__ inline uint32 pack2bf(float a, float b) {
    return (uint32)f2bf(a) | ((uint32)f2bf(b) << 16);
}

// SWAR unpack: one packed byte (int32 value 0..255, 4 crumbs little-endian)
// -> two uint32, each holding 2 bf16: r0 = {bf(c0), bf(c1)}, r1 = {bf(c2), bf(c3)}.
// crumb->bf16: 0->0x0000, 1->0x3F80 (+1), 2->0xBF80 (-1), 3->0x8000 (-0.0, harmless in MAC)
__device__ inline void unpack_byte(int v, uint32& r0, uint32& r1) {
    uint32 t0 = ((uint32)v & 3u) | (((uint32)v & 0xCu) << 14);         // c0 @ [1:0], c1 @ [17:16]
    uint32 t1 = (((uint32)v >> 4) & 3u) | (((uint32)v & 0xC0u) << 10); // c2, c3
    uint32 s0 = t0 >> 1;
    uint32 s1 = t1 >> 1;
    uint32 nz0 = (t0 ^ s0) & 0x00010001u;
    uint32 nz1 = (t1 ^ s1) & 0x00010001u;
    r0 = nz0 * 0x3F80u + ((s0 & 0x00010001u) << 15);
    r1 = nz1 * 0x3F80u + ((s1 & 0x00010001u) << 15);
}

__device__ inline float clipf(float y) {
    return fminf(fmaxf(y, -CLIP_VAL), CLIP_VAL);
}

// k-permuted fragment layout (unchanged):
// "group" g in [0,64) covers original k in [g*64, g*64+64).
// Within a group, lane quad q and k-step s in {0,1}:
//   MFMA k-slot q*8+j  <->  original k = g*64 + q*16 + s*8 + j
// pw side: lane(q,n) needs the 16B granule G = g*4+q of unit row n
//   (elements P..P+3, P = g*16+q*4; P,P+1 -> step s=0, P+2,P+3 -> step s=1).
// x side: granule idx = g*256 + s*128 + h*64 + lane holds 8 bf16:
//   j -> x[h*16 + (lane&15)][g*64 + (lane>>4)*16 + s*8 + j]

// Kernel 1: convert x [32][4096] fp32 -> bf16 in permuted A-fragment order.
// Single copy (R9: 8x replication caused HBM re-fetch under pw stream pressure).
__global__ __launch_bounds__(256) void convert_x_kernel(
    const float* __restrict__ x, uint4* __restrict__ ws) {
    int t = blockIdx.x * 256 + threadIdx.x;      // 0..16383 = granule idx
    int lane = t & 63;
    int h = (t >> 6) & 1;
    int s = (t >> 7) & 1;
    int g = t >> 8;
    int n = lane & 15;
    int q = lane >> 4;
    int b = h * 16 + n;
    int k0 = g * 64 + q * 16 + s * 8;
    const float4* src = (const float4*)(x + (size_t)b * IN_F + k0);
    float4 lo = src[0];
    float4 hi = src[1];
    uint4 o;
    o.x = pack2bf(lo.x, lo.y);
    o.y = pack2bf(lo.z, lo.w);
    o.z = pack2bf(hi.x, hi.y);
    o.w = pack2bf(hi.z, hi.w);
    ws[t] = o;
}

// Kernel 2: MFMA GEMM, v11 — contiguous staging + conflict-free swizzle,
// collision-free packing (fixes R10's overlap bug).
//
// Block's 64 KB pw tile = 64 "runs" of 1 KB (run R = quarter R%4 of unit row
// R/4). Each run: one global_load_lds with fully contiguous 1 KB global source.
// Run R placed at LDS byte R*1040 (1024 + 16 pad). 1040 = 65*16, 65 == 1 mod 8
// -> run base granule == R (mod 8): same bank rotation R10 wanted, disjoint
// runs (R10 placed run R at R*1024+(R&7)*16, which overlapped run R+1 whenever
// R&7==7 -> absmax 52).
// Fragment read (wave wid, iter i, lane q,n): R = n*4 + (wid>>2),
//   o = (wid&3)*16 + i*4 + q, addr = R*1040 + o*16.
//   bank group = (R + o) mod 8 = (4(n&1) + q + const) mod 8
//   -> 8 lanes per 4-bank group = conflict-free ds_read_b128
//   (R9 amplified probe: 1.285e7 conflict cycles with unswizzled layout).
// 64*1040 = 66560 B LDS -> 2 blocks/CU, 32 waves/CU.
__global__ __launch_bounds__(1024, 8) void ternary_mm_kernel(
    const uint4* __restrict__ xw,     // permuted bf16 x fragments (single copy)
    const int*   __restrict__ pw,     // [UNITS][PACKED] packed bytes as int32
    const float* __restrict__ scale,
    const float* __restrict__ bias,
    float*       __restrict__ out) {
    __shared__ int lds4[16640];       // 66560 B: swizzled pw tile, later reduce
    char* lds = (char*)lds4;

    const int tid  = threadIdx.x;
    const int wid  = tid >> 6;           // 0..15 = K-split index
    const int lane = tid & 63;
    const int q    = lane >> 4;          // quad 0..3
    const int n    = lane & 15;
    const int u0   = blockIdx.x << 4;    // 16 units per block
    const int g0   = wid << 2;           // first group (of 64 total)

    // ---- stage 64 KB pw tile: 64 contiguous-1KB DMA runs at stride 1040 ----
    {
        const char* src = (const char*)(pw + (size_t)u0 * PACKED);
        #pragma unroll
        for (int j = 0; j < 4; ++j) {
            const int Rs = j * 16 + wid;
            __builtin_amdgcn_global_load_lds(
                (const __attribute__((address_space(1))) uint32*)
                    (src + (Rs << 10) + (lane << 4)),
                (__attribute__((address_space(3))) uint32*)
                    (lds + Rs * 1040),
                16, 0, 0);
        }
    }

    // x fragments (prefetch first batch; __syncthreads drains vmcnt anyway)
    const uint4* xb = xw + (g0 << 8) + lane;
    uint4 xa0 = xb[0], xa1 = xb[64], xa2 = xb[128], xa3 = xb[192];

    __syncthreads();                     // DMA drained (vmcnt) + cross-wave vis

    f32x4 acc0 = {0.f,0.f,0.f,0.f};      // batches h0 (0-15)
    f32x4 acc1 = {0.f,0.f,0.f,0.f};      // batches h1 (16-31)

    // per-lane fragment base (iter i adds i*64 bytes)
    const int R = (n << 2) + (wid >> 2);
    const char* lb = lds + R * 1040 + ((wid & 3) << 8) + (q << 4);

    #pragma unroll
    for (int i = 0; i < 4; ++i) {
        uint4 xn0, xn1, xn2, xn3;
        if (i < 3) {                     // rolling 1-iter x prefetch
            const uint4* xi = xb + ((i + 1) << 8);
            xn0 = xi[0]; xn1 = xi[64]; xn2 = xi[128]; xn3 = xi[192];
        }
        int4 w4 = *(const int4*)(lb + (i << 6));   // conflict-free ds_read_b128

        uint4 fA, fB;                    // step 0 / step 1 weight frags
        unpack_byte(w4.x, fA.x, fA.y);
        unpack_byte(w4.y, fA.z, fA.w);
        unpack_byte(w4.z, fB.x, fB.y);
        unpack_byte(w4.w, fB.z, fB.w);
        bf16x8 vA = __builtin_bit_cast(bf16x8, fA);
        bf16x8 vB = __builtin_bit_cast(bf16x8, fB);

        acc0 = __builtin_amdgcn_mfma_f32_16x16x32_bf16(
            __builtin_bit_cast(bf16x8, xa0), vA, acc0, 0, 0, 0);
        acc1 = __builtin_amdgcn_mfma_f32_16x16x32_bf16(
            __builtin_bit_cast(bf16x8, xa1), vA, acc1, 0, 0, 0);
        acc0 = __builtin_amdgcn_mfma_f32_16x16x32_bf16(
            __builtin_bit_cast(bf16x8, xa2), vB, acc0, 0, 0, 0);
        acc1 = __builtin_amdgcn_mfma_f32_16x16x32_bf16(
            __builtin_bit_cast(bf16x8, xa3), vB, acc1, 0, 0, 0);

        if (i < 3) { xa0 = xn0; xa1 = xn1; xa2 = xn2; xa3 = xn3; }
    }

    __syncthreads();                     // all pw ds_reads done; alias LDS
    f32x4* red = (f32x4*)lds;            // [16 waves][2 h][64 lanes] = 32 KB
    red[(wid * 2 + 0) * 64 + lane] = acc0;
    red[(wid * 2 + 1) * 64 + lane] = acc1;
    __syncthreads();

    // Reduce 16 K-partials + epilogue. 128 active threads, one per (h, lane).
    if (tid < 128) {
        const int h = tid >> 6;
        const int l = tid & 63;
        f32x4 s = red[h * 64 + l];
        #pragma unroll
        for (int w = 1; w < 16; ++w) {
            f32x4 v = red[(w * 2 + h) * 64 + l];
            s[0] += v[0]; s[1] += v[1]; s[2] += v[2]; s[3] += v[3];
        }
        const int u  = u0 + (l & 15);
        const int b0 = h * 16 + ((l >> 4) << 2);   // row = (lane>>4)*4 + reg
        const float sc = scale[u];
        const float bi = bias[u];
        float* o = out + (size_t)b0 * UNITS + u;
        o[0 * UNITS] = clipf(s[0] * sc + bi);
        o[1 * UNITS] = clipf(s[1] * sc + bi);
        o[2 * UNITS] = clipf(s[2] * sc + bi);
        o[3 * UNITS] = clipf(s[3] * sc + bi);
    }
}

extern "C" void kernel_launch(void* const* d_in, const int* in_sizes, int n_in,
                              void* d_out, int out_size, void* d_ws, size_t ws_size,
                              hipStream_t stream) {
    const float* x     = (const float*)d_in[0];
    const int*   pw    = (const int*)d_in[1];
    const float* scale = (const float*)d_in[2];
    const float* bias  = (const float*)d_in[3];
    float* out = (float*)d_out;

    // ws usage: 32*4096 bf16 = 256 KB permuted x fragments (single copy)
    uint4* xw = (uint4*)d_ws;

    convert_x_kernel<<<64, 256, 0, stream>>>(x, xw);
    ternary_mm_kernel<<<UNITS / 16, 1024, 0, stream>>>(xw, pw, scale, bias, out);
}